// Round 3
// baseline (224.861 us; speedup 1.0000x reference)
//
#include <hip/hip_runtime.h>
#include <math.h>

// Causal SDPA, B=4 H=8 S=2048 D=64, scale = 1/sqrt(512)  (HIDDEN_SIZE=512).
// d_out (fp32!): [B,H,S,D] output O followed by [B,H,S,S] attn probs P.
// Inputs fp32. mask input ignored (statically causal, triu k=1).

#define S_LEN 2048
#define SCALE 0.04419417382415922f  // 1/sqrt(512)

typedef __attribute__((ext_vector_type(8))) short bf16x8;
typedef __attribute__((ext_vector_type(4))) float f32x4;

__device__ __forceinline__ short f2bf(float f) {
  unsigned u = __builtin_bit_cast(unsigned, f);
  u = (u + 0x7FFFu + ((u >> 16) & 1u)) >> 16;
  return (short)u;
}

__device__ __forceinline__ bf16x8 pack8(float4 a, float4 b) {
  bf16x8 t;
  t[0] = f2bf(a.x); t[1] = f2bf(a.y); t[2] = f2bf(a.z); t[3] = f2bf(a.w);
  t[4] = f2bf(b.x); t[5] = f2bf(b.y); t[6] = f2bf(b.z); t[7] = f2bf(b.w);
  return t;
}

// LDS tiles padded to 72 halfs/row (144 B): rows stay 16B-aligned for b128,
// and 144 % 128 = 16 rotates successive rows across bank groups.
__global__ __launch_bounds__(256, 2)
void sdpa_kernel(const float* Q, const float* K, const float* V,
                 float* outO, float* outP)
{
  __shared__ __align__(16) short ldsK[64][72];      // K tile   [k][d]
  __shared__ __align__(16) short ldsV[64][72];      // V^T tile [d][k]
  __shared__ __align__(16) short ldsP[4][16][72];   // per-wave P tile [q][k]

  const int tid  = threadIdx.x;
  const int lane = tid & 63;
  const int w    = tid >> 6;
  const int lrow = lane & 15;   // A-row / D-col lane index
  const int lgrp = lane >> 4;   // k-granule selector (A/B k = lgrp*8+e)

  // heavy q-tiles first: no load-imbalance tail
  const int qt = 31 - (blockIdx.x >> 5);
  const int bh = blockIdx.x & 31;
  const int q0 = qt << 6;

  // staging map: thread covers tile row sr, 16 floats starting at col sc
  const int sr = tid & 63;
  const int sc = (tid >> 6) << 4;

  // ---- Q fragments (A operand): lane holds Q[q0+16w+lrow][ks*32+lgrp*8 ..+7]
  bf16x8 qf[2];
  {
    const float* qb = Q + ((size_t)(bh * S_LEN + q0 + (w << 4) + lrow)) * 64;
#pragma unroll
    for (int ks = 0; ks < 2; ++ks) {
      const float* p = qb + ks * 32 + lgrp * 8;
      qf[ks] = pack8(*(const float4*)p, *(const float4*)(p + 4));
    }
  }

  float m_run[4] = {-INFINITY, -INFINITY, -INFINITY, -INFINITY};
  float l_run[4] = {0.f, 0.f, 0.f, 0.f};

  // ================= pass 1: exact row max + denominator =================
  for (int kt = 0; kt <= qt; ++kt) {
    __syncthreads();
    {
      const float* src = K + ((size_t)(bh * S_LEN + (kt << 6) + sr)) * 64 + sc;
      float4 a0 = ((const float4*)src)[0];
      float4 a1 = ((const float4*)src)[1];
      float4 a2 = ((const float4*)src)[2];
      float4 a3 = ((const float4*)src)[3];
      *(bf16x8*)&ldsK[sr][sc]     = pack8(a0, a1);
      *(bf16x8*)&ldsK[sr][sc + 8] = pack8(a2, a3);
    }
    __syncthreads();

    f32x4 acc[4];
#pragma unroll
    for (int nt = 0; nt < 4; ++nt) {
      f32x4 a = {0.f, 0.f, 0.f, 0.f};
#pragma unroll
      for (int ks = 0; ks < 2; ++ks) {
        bf16x8 bfrag = *(const bf16x8*)&ldsK[nt * 16 + lrow][ks * 32 + lgrp * 8];
        a = __builtin_amdgcn_mfma_f32_16x16x32_bf16(qf[ks], bfrag, a, 0, 0, 0);
      }
      acc[nt] = a;
    }

#pragma unroll
    for (int rg = 0; rg < 4; ++rg) {
      const int row = q0 + (w << 4) + (lgrp << 2) + rg;  // D row = 4*lgrp+rg
      float s[4];
#pragma unroll
      for (int nt = 0; nt < 4; ++nt) {
        const int col = (kt << 6) + nt * 16 + lrow;      // D col = lrow
        s[nt] = (col > row) ? -INFINITY : acc[nt][rg] * SCALE;
      }
      float tmax = fmaxf(fmaxf(s[0], s[1]), fmaxf(s[2], s[3]));
      tmax = fmaxf(tmax, __shfl_xor(tmax, 1));
      tmax = fmaxf(tmax, __shfl_xor(tmax, 2));
      tmax = fmaxf(tmax, __shfl_xor(tmax, 4));
      tmax = fmaxf(tmax, __shfl_xor(tmax, 8));
      const float nm = fmaxf(m_run[rg], tmax);
      float ps = __expf(s[0] - nm) + __expf(s[1] - nm)
               + __expf(s[2] - nm) + __expf(s[3] - nm);
      ps += __shfl_xor(ps, 1);
      ps += __shfl_xor(ps, 2);
      ps += __shfl_xor(ps, 4);
      ps += __shfl_xor(ps, 8);
      l_run[rg] = l_run[rg] * __expf(m_run[rg] - nm) + ps;
      m_run[rg] = nm;
    }
  }

  float inv_l[4];
#pragma unroll
  for (int rg = 0; rg < 4; ++rg) inv_l[rg] = 1.f / l_run[rg];

  f32x4 oacc[4];
#pragma unroll
  for (int nt = 0; nt < 4; ++nt) oacc[nt] = (f32x4){0.f, 0.f, 0.f, 0.f};

  // ================= pass 2: probs, attn store, PV =================
  for (int kt = 0; kt <= qt; ++kt) {
    __syncthreads();
    {
      const float* srcK = K + ((size_t)(bh * S_LEN + (kt << 6) + sr)) * 64 + sc;
      float4 a0 = ((const float4*)srcK)[0];
      float4 a1 = ((const float4*)srcK)[1];
      float4 a2 = ((const float4*)srcK)[2];
      float4 a3 = ((const float4*)srcK)[3];
      *(bf16x8*)&ldsK[sr][sc]     = pack8(a0, a1);
      *(bf16x8*)&ldsK[sr][sc + 8] = pack8(a2, a3);

      const float* srcV = V + ((size_t)(bh * S_LEN + (kt << 6) + sr)) * 64 + sc;
      float4 b0 = ((const float4*)srcV)[0];
      float4 b1 = ((const float4*)srcV)[1];
      float4 b2 = ((const float4*)srcV)[2];
      float4 b3 = ((const float4*)srcV)[3];
      const float vv[16] = {b0.x, b0.y, b0.z, b0.w, b1.x, b1.y, b1.z, b1.w,
                            b2.x, b2.y, b2.z, b2.w, b3.x, b3.y, b3.z, b3.w};
#pragma unroll
      for (int j = 0; j < 16; ++j) ldsV[sc + j][sr] = f2bf(vv[j]);  // transpose
    }
    __syncthreads();

    f32x4 acc[4];
#pragma unroll
    for (int nt = 0; nt < 4; ++nt) {
      f32x4 a = {0.f, 0.f, 0.f, 0.f};
#pragma unroll
      for (int ks = 0; ks < 2; ++ks) {
        bf16x8 bfrag = *(const bf16x8*)&ldsK[nt * 16 + lrow][ks * 32 + lgrp * 8];
        a = __builtin_amdgcn_mfma_f32_16x16x32_bf16(qf[ks], bfrag, a, 0, 0, 0);
      }
      acc[nt] = a;
    }

#pragma unroll
    for (int rg = 0; rg < 4; ++rg) {
      const int row = q0 + (w << 4) + (lgrp << 2) + rg;
      const int rl  = (lgrp << 2) + rg;
      const size_t prow = (size_t)bh * S_LEN * S_LEN + (size_t)row * S_LEN;
#pragma unroll
      for (int nt = 0; nt < 4; ++nt) {
        const int col = (kt << 6) + nt * 16 + lrow;
        const float sv = (col > row) ? -INFINITY : acc[nt][rg] * SCALE;
        const float p  = __expf(sv - m_run[rg]) * inv_l[rg];
        ldsP[w][rl][nt * 16 + lrow] = f2bf(p);   // MFMA operand (bf16)
        outP[prow + col] = p;                    // exact prob store (fp32)
      }
    }

    // PV: A = own-wave P tile (16q x 64k), B = V^T tile; same-wave LDS
    // write->read (ldsP[w] is wave-private; compiler orders via lgkmcnt).
#pragma unroll
    for (int nt = 0; nt < 4; ++nt) {
#pragma unroll
      for (int ks = 0; ks < 2; ++ks) {
        bf16x8 pa = *(const bf16x8*)&ldsP[w][lrow][ks * 32 + lgrp * 8];
        bf16x8 vb = *(const bf16x8*)&ldsV[nt * 16 + lrow][ks * 32 + lgrp * 8];
        oacc[nt] = __builtin_amdgcn_mfma_f32_16x16x32_bf16(pa, vb, oacc[nt], 0, 0, 0);
      }
    }
  }

  // ---- zero the strictly-masked column range (cols >= (qt+1)*64) ----
  {
    const int kz = (qt + 1) << 6;
    if (kz < S_LEN) {
      const float4 z = {0.f, 0.f, 0.f, 0.f};
      for (int row = 0; row < 64; ++row) {
        const size_t base = (size_t)bh * S_LEN * S_LEN + (size_t)(q0 + row) * S_LEN;
        for (int c = kz + (tid << 2); c < S_LEN; c += 256 * 4) {
          *(float4*)(outP + base + c) = z;
        }
      }
    }
  }

  // ---- write O (fp32): D row = 4*lgrp+rg, D col(=d) = nt*16+lrow ----
#pragma unroll
  for (int nt = 0; nt < 4; ++nt) {
#pragma unroll
    for (int rg = 0; rg < 4; ++rg) {
      const int rl = (lgrp << 2) + rg;
      const int d  = nt * 16 + lrow;
      outO[((size_t)(bh * S_LEN + q0 + (w << 4) + rl)) * 64 + d] = oacc[nt][rg];
    }
  }
}

extern "C" void kernel_launch(void* const* d_in, const int* in_sizes, int n_in,
                              void* d_out, int out_size, void* d_ws, size_t ws_size,
                              hipStream_t stream) {
  const float* Q = (const float*)d_in[0];
  const float* K = (const float*)d_in[1];
  const float* V = (const float*)d_in[2];
  // d_in[3] (mask) is statically causal -> not read.
  float* outO = (float*)d_out;
  float* outP = outO + (size_t)32 * S_LEN * 64;  // after [B,H,S,D] output
  sdpa_kernel<<<dim3(32 * 32), dim3(256), 0, stream>>>(Q, K, V, outO, outP);
}

// Round 4
// 221.461 us; speedup vs baseline: 1.0154x; 1.0154x over previous
//
#include <hip/hip_runtime.h>
#include <math.h>

// Causal SDPA, B=4 H=8 S=2048 D=64, scale = 1/sqrt(512)  (HIDDEN_SIZE=512).
// d_out (fp32): [B,H,S,D] output O followed by [B,H,S,S] attn probs P.
// Inputs fp32. mask input ignored (statically causal, triu k=1).
//
// Swapped QK^T (mfma(K,Q) -> S^T): each lane owns one q-row; P stores are
// float4, LDS P stores are b64, softmax reduce is 2 shuffles.

#define S_LEN 2048
#define SCALE 0.04419417382415922f  // 1/sqrt(512)

typedef __attribute__((ext_vector_type(8))) short bf16x8;
typedef __attribute__((ext_vector_type(4))) short bf16x4;
typedef __attribute__((ext_vector_type(4))) float f32x4;

__device__ __forceinline__ short f2bf(float f) {
  unsigned u = __builtin_bit_cast(unsigned, f);
  u = (u + 0x7FFFu + ((u >> 16) & 1u)) >> 16;
  return (short)u;
}

__device__ __forceinline__ bf16x8 pack8(float4 a, float4 b) {
  bf16x8 t;
  t[0] = f2bf(a.x); t[1] = f2bf(a.y); t[2] = f2bf(a.z); t[3] = f2bf(a.w);
  t[4] = f2bf(b.x); t[5] = f2bf(b.y); t[6] = f2bf(b.z); t[7] = f2bf(b.w);
  return t;
}

// LDS rows padded to 72 halfs (144 B): 16B-aligned rows, bank-group rotation.
__global__ __launch_bounds__(256, 2)
void sdpa_kernel(const float* Q, const float* K, const float* V,
                 float* outO, float* outP)
{
  __shared__ __align__(16) short ldsK[64][72];      // K tile   [k][d]
  __shared__ __align__(16) short ldsV[64][72];      // V^T tile [d][k]
  __shared__ __align__(16) short ldsP[4][16][72];   // per-wave P tile [q][k]

  const int tid  = threadIdx.x;
  const int lane = tid & 63;
  const int w    = tid >> 6;
  const int lrow = lane & 15;   // q-row lane index (S^T cols / O d-cols)
  const int lgrp = lane >> 4;

  // heavy q-tiles first: no load-imbalance tail
  const int qt = 31 - (blockIdx.x >> 5);
  const int bh = blockIdx.x & 31;
  const int q0 = qt << 6;
  const int qrow = q0 + (w << 4) + lrow;   // this lane's q row

  // staging map: thread covers tile row sr, 16 floats from col sc
  const int sr = tid & 63;
  const int sc = (tid >> 6) << 4;

  // Q fragment (B operand of S^T = K*Q^T): lane holds Q[qrow][ks*32+lgrp*8..+7]
  bf16x8 qf[2];
  {
    const float* qb = Q + ((size_t)(bh * S_LEN + qrow)) * 64;
#pragma unroll
    for (int ks = 0; ks < 2; ++ks) {
      const float* p = qb + ks * 32 + lgrp * 8;
      qf[ks] = pack8(*(const float4*)p, *(const float4*)(p + 4));
    }
  }

  float m_run = -INFINITY;
  float l_run = 0.f;

  // ================= pass 1: exact row max + denominator =================
  for (int kt = 0; kt <= qt; ++kt) {
    __syncthreads();
    {
      const float* src = K + ((size_t)(bh * S_LEN + (kt << 6) + sr)) * 64 + sc;
      float4 a0 = ((const float4*)src)[0];
      float4 a1 = ((const float4*)src)[1];
      float4 a2 = ((const float4*)src)[2];
      float4 a3 = ((const float4*)src)[3];
      *(bf16x8*)&ldsK[sr][sc]     = pack8(a0, a1);
      *(bf16x8*)&ldsK[sr][sc + 8] = pack8(a2, a3);
    }
    __syncthreads();

    f32x4 acc[4];
#pragma unroll
    for (int nt = 0; nt < 4; ++nt) {
      f32x4 a = {0.f, 0.f, 0.f, 0.f};
#pragma unroll
      for (int ks = 0; ks < 2; ++ks) {
        bf16x8 kfrag = *(const bf16x8*)&ldsK[nt * 16 + lrow][ks * 32 + lgrp * 8];
        a = __builtin_amdgcn_mfma_f32_16x16x32_bf16(kfrag, qf[ks], a, 0, 0, 0);
      }
      acc[nt] = a;
    }

    // scale (+ mask only on diagonal tile); lane's 16 regs all belong to qrow
    if (kt == qt) {
#pragma unroll
      for (int nt = 0; nt < 4; ++nt)
#pragma unroll
        for (int rg = 0; rg < 4; ++rg) {
          const int col = (kt << 6) + nt * 16 + (lgrp << 2) + rg;
          acc[nt][rg] = (col > qrow) ? -INFINITY : acc[nt][rg] * SCALE;
        }
    } else {
#pragma unroll
      for (int nt = 0; nt < 4; ++nt)
#pragma unroll
        for (int rg = 0; rg < 4; ++rg) acc[nt][rg] *= SCALE;
    }

    float tm = -INFINITY;
#pragma unroll
    for (int nt = 0; nt < 4; ++nt)
#pragma unroll
      for (int rg = 0; rg < 4; ++rg) tm = fmaxf(tm, acc[nt][rg]);
    tm = fmaxf(tm, __shfl_xor(tm, 16));
    tm = fmaxf(tm, __shfl_xor(tm, 32));
    const float nm = fmaxf(m_run, tm);

    float ps = 0.f;
#pragma unroll
    for (int nt = 0; nt < 4; ++nt)
#pragma unroll
      for (int rg = 0; rg < 4; ++rg) ps += __expf(acc[nt][rg] - nm);
    ps += __shfl_xor(ps, 16);
    ps += __shfl_xor(ps, 32);

    l_run = l_run * __expf(m_run - nm) + ps;
    m_run = nm;
  }

  const float inv_l = 1.f / l_run;

  f32x4 oacc[4];
#pragma unroll
  for (int nt = 0; nt < 4; ++nt) oacc[nt] = (f32x4){0.f, 0.f, 0.f, 0.f};

  const size_t pbase = (size_t)bh * S_LEN * S_LEN + (size_t)qrow * S_LEN;

  // ================= pass 2: probs, attn store, PV =================
  for (int kt = 0; kt <= qt; ++kt) {
    __syncthreads();
    {
      const float* srcK = K + ((size_t)(bh * S_LEN + (kt << 6) + sr)) * 64 + sc;
      float4 a0 = ((const float4*)srcK)[0];
      float4 a1 = ((const float4*)srcK)[1];
      float4 a2 = ((const float4*)srcK)[2];
      float4 a3 = ((const float4*)srcK)[3];
      *(bf16x8*)&ldsK[sr][sc]     = pack8(a0, a1);
      *(bf16x8*)&ldsK[sr][sc + 8] = pack8(a2, a3);

      const float* srcV = V + ((size_t)(bh * S_LEN + (kt << 6) + sr)) * 64 + sc;
      float4 b0 = ((const float4*)srcV)[0];
      float4 b1 = ((const float4*)srcV)[1];
      float4 b2 = ((const float4*)srcV)[2];
      float4 b3 = ((const float4*)srcV)[3];
      const float vv[16] = {b0.x, b0.y, b0.z, b0.w, b1.x, b1.y, b1.z, b1.w,
                            b2.x, b2.y, b2.z, b2.w, b3.x, b3.y, b3.z, b3.w};
#pragma unroll
      for (int j = 0; j < 16; ++j) ldsV[sc + j][sr] = f2bf(vv[j]);  // transpose
    }
    __syncthreads();

    f32x4 acc[4];
#pragma unroll
    for (int nt = 0; nt < 4; ++nt) {
      f32x4 a = {0.f, 0.f, 0.f, 0.f};
#pragma unroll
      for (int ks = 0; ks < 2; ++ks) {
        bf16x8 kfrag = *(const bf16x8*)&ldsK[nt * 16 + lrow][ks * 32 + lgrp * 8];
        a = __builtin_amdgcn_mfma_f32_16x16x32_bf16(kfrag, qf[ks], a, 0, 0, 0);
      }
      acc[nt] = a;
    }

    if (kt == qt) {
#pragma unroll
      for (int nt = 0; nt < 4; ++nt)
#pragma unroll
        for (int rg = 0; rg < 4; ++rg) {
          const int col = (kt << 6) + nt * 16 + (lgrp << 2) + rg;
          acc[nt][rg] = (col > qrow) ? -INFINITY : acc[nt][rg] * SCALE;
        }
    } else {
#pragma unroll
      for (int nt = 0; nt < 4; ++nt)
#pragma unroll
        for (int rg = 0; rg < 4; ++rg) acc[nt][rg] *= SCALE;
    }

    // probabilities: float4 global store + b64 LDS store per nt
#pragma unroll
    for (int nt = 0; nt < 4; ++nt) {
      float4 p4;
      p4.x = __expf(acc[nt][0] - m_run) * inv_l;
      p4.y = __expf(acc[nt][1] - m_run) * inv_l;
      p4.z = __expf(acc[nt][2] - m_run) * inv_l;
      p4.w = __expf(acc[nt][3] - m_run) * inv_l;
      *(float4*)(outP + pbase + (kt << 6) + nt * 16 + (lgrp << 2)) = p4;
      bf16x4 pb;
      pb[0] = f2bf(p4.x); pb[1] = f2bf(p4.y);
      pb[2] = f2bf(p4.z); pb[3] = f2bf(p4.w);
      *(bf16x4*)&ldsP[w][lrow][nt * 16 + (lgrp << 2)] = pb;
    }

    // PV: A = own-wave P tile (16q x 64k), B = V^T tile (same-wave LDS
    // write->read; ldsP[w] is wave-private, ordered by lgkmcnt).
#pragma unroll
    for (int nt = 0; nt < 4; ++nt) {
#pragma unroll
      for (int ks = 0; ks < 2; ++ks) {
        bf16x8 pa = *(const bf16x8*)&ldsP[w][lrow][ks * 32 + lgrp * 8];
        bf16x8 vb = *(const bf16x8*)&ldsV[nt * 16 + lrow][ks * 32 + lgrp * 8];
        oacc[nt] = __builtin_amdgcn_mfma_f32_16x16x32_bf16(pa, vb, oacc[nt], 0, 0, 0);
      }
    }
  }

  // ---- zero the strictly-masked column range (cols >= (qt+1)*64) ----
  {
    const int kz = (qt + 1) << 6;
    if (kz < S_LEN) {
      const float4 z = {0.f, 0.f, 0.f, 0.f};
      for (int row = 0; row < 64; ++row) {
        const size_t base = (size_t)bh * S_LEN * S_LEN + (size_t)(q0 + row) * S_LEN;
        for (int c = kz + (tid << 2); c < S_LEN; c += 256 * 4) {
          *(float4*)(outP + base + c) = z;
        }
      }
    }
  }

  // ---- write O (fp32): O row = q0+16w+4*lgrp+rg, col d = nt*16+lrow ----
#pragma unroll
  for (int nt = 0; nt < 4; ++nt) {
#pragma unroll
    for (int rg = 0; rg < 4; ++rg) {
      const int rl = (lgrp << 2) + rg;
      const int d  = nt * 16 + lrow;
      outO[((size_t)(bh * S_LEN + q0 + (w << 4) + rl)) * 64 + d] = oacc[nt][rg];
    }
  }
}

extern "C" void kernel_launch(void* const* d_in, const int* in_sizes, int n_in,
                              void* d_out, int out_size, void* d_ws, size_t ws_size,
                              hipStream_t stream) {
  const float* Q = (const float*)d_in[0];
  const float* K = (const float*)d_in[1];
  const float* V = (const float*)d_in[2];
  // d_in[3] (mask) is statically causal -> not read.
  float* outO = (float*)d_out;
  float* outP = outO + (size_t)32 * S_LEN * 64;  // after [B,H,S,D] output
  sdpa_kernel<<<dim3(32 * 32), dim3(256), 0, stream>>>(Q, K, V, outO, outP);
}